// Round 6
// baseline (2389.953 us; speedup 1.0000x reference)
//
#include <hip/hip_runtime.h>
#include <hip/hip_bf16.h>
#include <stdint.h>

// Problem constants
#define TT 4
#define BE 16
#define BB 64          // TT * BE
#define CC 512
#define NN 512
#define NH 8
#define GD 64          // CC / NH
#define NW 16          // NN/32 packed words per (b,c) row
#define TAU 0.5f
#define THRESH 1.0f
#define SCALE 0.125f
#define EPS 1e-5f

// ---------------------------------------------------------------------------
// Kernel 1: fused 1x1-conv (GEMM) + BatchNorm + LIF over T -> bit-packed spikes.
// Grid: (NN/64, CC/64, BE). Block: 256 (16x16), 4x4 micro-tile. Membrane in regs.
// ---------------------------------------------------------------------------
__global__ __launch_bounds__(256) void conv_bn_lif_kernel(
    const float* __restrict__ x,      // [BB, CC, NN] fp32
    const float* __restrict__ W,      // [CC, CC]  (out, in) fp32
    const float* __restrict__ bn_g,   // [4, CC]
    const float* __restrict__ bn_b,
    const float* __restrict__ bn_m,
    const float* __restrict__ bn_v,
    int sel,
    uint32_t* __restrict__ out_spk)   // [BB*CC, NW] packed
{
    __shared__ float Ws[16][64 + 1];
    __shared__ float Xs[16][64 + 1];
    __shared__ unsigned char Ss[64][64];   // spike byte tile (c_local, n_local)

    const int tid = threadIdx.x;
    const int tx = tid & 15;
    const int ty = tid >> 4;
    const int n0 = blockIdx.x * 64;
    const int c0 = blockIdx.y * 64;
    const int be = blockIdx.z;

    float inv_c[4], add_c[4];
#pragma unroll
    for (int i = 0; i < 4; ++i) {
        int c = c0 + ty + 16 * i;
        float g = bn_g[sel * CC + c];
        float b = bn_b[sel * CC + c];
        float m = bn_m[sel * CC + c];
        float v = bn_v[sel * CC + c];
        float inv = g / sqrtf(v + EPS);
        inv_c[i] = inv;
        add_c[i] = b - m * inv;
    }

    float mem[4][4];
#pragma unroll
    for (int i = 0; i < 4; ++i)
#pragma unroll
        for (int j = 0; j < 4; ++j) mem[i][j] = 0.0f;

    for (int t = 0; t < TT; ++t) {
        const int b = t * BE + be;
        const float* xb = x + (size_t)b * CC * NN;

        float acc[4][4];
#pragma unroll
        for (int i = 0; i < 4; ++i)
#pragma unroll
            for (int j = 0; j < 4; ++j) acc[i][j] = 0.0f;

        for (int k0 = 0; k0 < CC; k0 += 16) {
#pragma unroll
            for (int i = tid; i < 1024; i += 256) {
                int kk = i & 15;
                int r = i >> 4;
                Ws[kk][r] = W[(size_t)(c0 + r) * CC + k0 + kk];
            }
#pragma unroll
            for (int i = tid; i < 1024; i += 256) {
                int col = i & 63;
                int kk = i >> 6;
                Xs[kk][col] = xb[(size_t)(k0 + kk) * NN + n0 + col];
            }
            __syncthreads();

#pragma unroll
            for (int kk = 0; kk < 16; ++kk) {
                float a[4], bvals[4];
#pragma unroll
                for (int i = 0; i < 4; ++i) a[i] = Ws[kk][ty + 16 * i];
#pragma unroll
                for (int j = 0; j < 4; ++j) bvals[j] = Xs[kk][tx + 16 * j];
#pragma unroll
                for (int i = 0; i < 4; ++i)
#pragma unroll
                    for (int j = 0; j < 4; ++j) acc[i][j] += a[i] * bvals[j];
            }
            __syncthreads();
        }

        // BN + LIF -> spike bytes into LDS tile
#pragma unroll
        for (int i = 0; i < 4; ++i) {
#pragma unroll
            for (int j = 0; j < 4; ++j) {
                float y = acc[i][j] * inv_c[i] + add_c[i];
                float m2 = mem[i][j] * TAU + y;
                bool s = m2 > THRESH;
                Ss[ty + 16 * i][tx + 16 * j] = s ? 1 : 0;
                mem[i][j] = s ? 0.0f : m2;
            }
        }
        __syncthreads();

        // pack: 128 threads, each builds one 32-bit word (c_local, half w)
        if (tid < 128) {
            int c_local = tid >> 1;
            int w = tid & 1;
            const uint32_t* row = (const uint32_t*)Ss[c_local];
            uint32_t word = 0;
#pragma unroll
            for (int k = 0; k < 8; ++k) {
                uint32_t u = row[w * 8 + k];
                word |= ((u & 1u) | ((u >> 7) & 2u) | ((u >> 14) & 4u) | ((u >> 21) & 8u)) << (k * 4);
            }
            out_spk[(size_t)(b * CC + c0 + c_local) * NW + (n0 >> 5) + w] = word;
        }
        // Ss next written only after the t+1 k0-loop barriers -> safe.
    }
}

// ---------------------------------------------------------------------------
// Kernel 2: fused attention + LIF3 on packed spikes.
// out[d][n] = SCALE * sum_dp M[d][dp] * q[dp][n],  M[d][dp] = popc(v[d]&k[dp]).
// Grid: (4 n-chunks, NH, BE). Block 256. Loops t inside; membrane in registers.
// ---------------------------------------------------------------------------
__global__ __launch_bounds__(256) void attn_lif_kernel(
    const uint32_t* __restrict__ qp,
    const uint32_t* __restrict__ kp,
    const uint32_t* __restrict__ vp,
    uint32_t* __restrict__ s3p)
{
    __shared__ uint32_t kL[64][NW + 1];
    __shared__ uint32_t vL[64][NW + 1];
    __shared__ float    Msh[64][64 + 1];
    __shared__ uint32_t qL[64][5];

    const int tid = threadIdx.x;
    const int nchunk = blockIdx.x;          // 0..3, each = 4 words = 128 n
    const int h = blockIdx.y;
    const int be = blockIdx.z;
    const int d_own = tid >> 2;
    const int nw_own = tid & 3;

    float mem[32];
#pragma unroll
    for (int i = 0; i < 32; ++i) mem[i] = 0.0f;

    for (int t = 0; t < TT; ++t) {
        const int b = t * BE + be;
        const size_t base_row = (size_t)(b * CC + h * GD);

        for (int i = tid; i < 64 * NW; i += 256) {
            int r = i >> 4;
            int w = i & (NW - 1);
            kL[r][w] = kp[(base_row + r) * NW + w];
            vL[r][w] = vp[(base_row + r) * NW + w];
        }
        {
            int r = tid >> 2;
            int w = tid & 3;
            qL[r][w] = qp[(base_row + r) * NW + nchunk * 4 + w];
        }
        __syncthreads();

        // M[d][dp] = popcount over 16 words
        for (int e = tid; e < 64 * 64; e += 256) {
            int d = e >> 6;
            int dp = e & 63;
            int s = 0;
#pragma unroll
            for (int w = 0; w < NW; ++w) s += __popc(vL[d][w] & kL[dp][w]);
            Msh[d][dp] = (float)s;
        }
        __syncthreads();

        // phase 2: accumulate 32 outputs per thread
        float acc[32];
#pragma unroll
        for (int i = 0; i < 32; ++i) acc[i] = 0.0f;

        for (int dp = 0; dp < 64; ++dp) {
            float Mv = Msh[d_own][dp];
            uint32_t w = qL[dp][nw_own];
#pragma unroll
            for (int b2 = 0; b2 < 32; ++b2) {
                acc[b2] += ((w >> b2) & 1u) ? Mv : 0.0f;
            }
        }

        // LIF + pack spike word
        uint32_t sw = 0;
#pragma unroll
        for (int b2 = 0; b2 < 32; ++b2) {
            float m2 = mem[b2] * TAU + SCALE * acc[b2];
            bool s = m2 > THRESH;
            sw |= (s ? 1u : 0u) << b2;
            mem[b2] = s ? 0.0f : m2;
        }
        s3p[(base_row + d_own) * NW + nchunk * 4 + nw_own] = sw;
        __syncthreads();   // protect kL/vL/qL/Msh before next t restage
    }
}

// ---------------------------------------------------------------------------
// Kernel 3: projection conv + BN on packed spikes -> fp32 output.
// Grid (NN/64, CC/64, BB). Block 256, 4x4 micro-tile.
// ---------------------------------------------------------------------------
__global__ __launch_bounds__(256) void proj_kernel(
    const uint32_t* __restrict__ s3p,          // [BB*CC, NW] packed
    const float* __restrict__ W,               // [CC, CC] fp32
    const float* __restrict__ bn_g,
    const float* __restrict__ bn_b,
    const float* __restrict__ bn_m,
    const float* __restrict__ bn_v,
    float* __restrict__ out)                   // [BB, CC, NN] fp32
{
    __shared__ float Ws[16][64 + 1];
    __shared__ float Xs[16][64 + 1];

    const int tid = threadIdx.x;
    const int tx = tid & 15;
    const int ty = tid >> 4;
    const int n0 = blockIdx.x * 64;
    const int c0 = blockIdx.y * 64;
    const int b = blockIdx.z;

    float inv_c[4], add_c[4];
#pragma unroll
    for (int i = 0; i < 4; ++i) {
        int c = c0 + ty + 16 * i;
        float g = bn_g[3 * CC + c];
        float bt = bn_b[3 * CC + c];
        float m = bn_m[3 * CC + c];
        float v = bn_v[3 * CC + c];
        float inv = g / sqrtf(v + EPS);
        inv_c[i] = inv;
        add_c[i] = bt - m * inv;
    }

    float acc[4][4];
#pragma unroll
    for (int i = 0; i < 4; ++i)
#pragma unroll
        for (int j = 0; j < 4; ++j) acc[i][j] = 0.0f;

    for (int k0 = 0; k0 < CC; k0 += 16) {
#pragma unroll
        for (int i = tid; i < 1024; i += 256) {
            int kk = i & 15;
            int r = i >> 4;
            Ws[kk][r] = W[(size_t)(c0 + r) * CC + k0 + kk];
        }
#pragma unroll
        for (int i = tid; i < 1024; i += 256) {
            int col = i & 63;
            int kk = i >> 6;
            uint32_t word = s3p[(size_t)(b * CC + k0 + kk) * NW + (n0 >> 5) + (col >> 5)];
            Xs[kk][col] = (float)((word >> (col & 31)) & 1u);
        }
        __syncthreads();

#pragma unroll
        for (int kk = 0; kk < 16; ++kk) {
            float a[4], bvals[4];
#pragma unroll
            for (int i = 0; i < 4; ++i) a[i] = Ws[kk][ty + 16 * i];
#pragma unroll
            for (int j = 0; j < 4; ++j) bvals[j] = Xs[kk][tx + 16 * j];
#pragma unroll
            for (int i = 0; i < 4; ++i)
#pragma unroll
                for (int j = 0; j < 4; ++j) acc[i][j] += a[i] * bvals[j];
        }
        __syncthreads();
    }

    float* ob = out + (size_t)b * CC * NN;
#pragma unroll
    for (int i = 0; i < 4; ++i) {
        int c = c0 + ty + 16 * i;
#pragma unroll
        for (int j = 0; j < 4; ++j) {
            int n = n0 + tx + 16 * j;
            ob[(size_t)c * NN + n] = acc[i][j] * inv_c[i] + add_c[i];
        }
    }
}

// ---------------------------------------------------------------------------
extern "C" void kernel_launch(void* const* d_in, const int* in_sizes, int n_in,
                              void* d_out, int out_size, void* d_ws, size_t ws_size,
                              hipStream_t stream) {
    const float* x     = (const float*)d_in[0];
    const float* wq    = (const float*)d_in[1];
    const float* wk    = (const float*)d_in[2];
    const float* wv    = (const float*)d_in[3];
    const float* wproj = (const float*)d_in[4];
    const float* bng   = (const float*)d_in[5];
    const float* bnb   = (const float*)d_in[6];
    const float* bnm   = (const float*)d_in[7];
    const float* bnv   = (const float*)d_in[8];

    const size_t PK = (size_t)BB * CC * NW;            // 524288 words = 2 MiB
    uint32_t* qp  = (uint32_t*)d_ws;
    uint32_t* kp  = qp + PK;
    uint32_t* vp  = kp + PK;
    uint32_t* s3p = vp + PK;                           // total 8 MiB

    dim3 gconv(NN / 64, CC / 64, BE);
    conv_bn_lif_kernel<<<gconv, 256, 0, stream>>>(x, wq, bng, bnb, bnm, bnv, 0, qp);
    conv_bn_lif_kernel<<<gconv, 256, 0, stream>>>(x, wk, bng, bnb, bnm, bnv, 1, kp);
    conv_bn_lif_kernel<<<gconv, 256, 0, stream>>>(x, wv, bng, bnb, bnm, bnv, 2, vp);

    dim3 gattn(4, NH, BE);
    attn_lif_kernel<<<gattn, 256, 0, stream>>>(qp, kp, vp, s3p);

    dim3 gproj(NN / 64, CC / 64, BB);
    proj_kernel<<<gproj, 256, 0, stream>>>(s3p, wproj, bng, bnb, bnm, bnv, (float*)d_out);
}

// Round 7
// 2347.314 us; speedup vs baseline: 1.0182x; 1.0182x over previous
//
#include <hip/hip_runtime.h>
#include <hip/hip_bf16.h>
#include <stdint.h>

// Problem constants
#define TT 4
#define BE 16
#define BB 64          // TT * BE
#define CC 512
#define NN 512
#define NH 8
#define GD 64          // CC / NH
#define NW 16          // NN/32 packed words per (b,c) row
#define TAU 0.5f
#define THRESH 1.0f
#define SCALE 0.125f
#define EPS 1e-5f

// ---------------------------------------------------------------------------
// Kernel 1: FUSED q/k/v 1x1-conv + BN + LIF over T -> bit-packed spikes.
// Grid: (NN/64, CC/64, BE). Block 256 (16x16 logical), 4x4 float4 micro-tile,
// x-fragment shared across the 3 GEMMs (48 FMA per 4 ds_read_b128).
// Spikes packed via octet shfl-OR, stored straight to global (no LDS tile).
// ---------------------------------------------------------------------------
__global__ __launch_bounds__(256) void conv_qkv_kernel(
    const float* __restrict__ x,      // [BB, CC, NN]
    const float* __restrict__ Wq,     // [CC, CC] (out, in)
    const float* __restrict__ Wk,
    const float* __restrict__ Wv,
    const float* __restrict__ bn_g,   // [4, CC]
    const float* __restrict__ bn_b,
    const float* __restrict__ bn_m,
    const float* __restrict__ bn_v,
    uint32_t* __restrict__ qp,        // [BB*CC, NW] packed
    uint32_t* __restrict__ kp,
    uint32_t* __restrict__ vp)
{
    __shared__ float Xs[16][68];      // [kk][col], pad->b128-aligned rows
    __shared__ float Ws[3][16][68];   // [w][kk][row]

    const int tid = threadIdx.x;
    const int tx = tid & 15;          // col group: cols 4tx..4tx+3
    const int ty = tid >> 4;          // row group: rows 4ty..4ty+3
    const int n0 = blockIdx.x * 64;
    const int c0 = blockIdx.y * 64;
    const int be = blockIdx.z;

    const float* const Wall[3] = {Wq, Wk, Wv};
    uint32_t* const outp[3] = {qp, kp, vp};

    float inv_c[3][4], add_c[3][4];
#pragma unroll
    for (int w = 0; w < 3; ++w) {
#pragma unroll
        for (int i = 0; i < 4; ++i) {
            int c = c0 + 4 * ty + i;
            float g = bn_g[w * CC + c];
            float b = bn_b[w * CC + c];
            float m = bn_m[w * CC + c];
            float v = bn_v[w * CC + c];
            float inv = g / sqrtf(v + EPS);
            inv_c[w][i] = inv;
            add_c[w][i] = b - m * inv;
        }
    }

    float mem[3][4][4];
#pragma unroll
    for (int w = 0; w < 3; ++w)
#pragma unroll
        for (int i = 0; i < 4; ++i)
#pragma unroll
            for (int j = 0; j < 4; ++j) mem[w][i][j] = 0.0f;

    for (int t = 0; t < TT; ++t) {
        const int b = t * BE + be;
        const float* xb = x + (size_t)b * CC * NN;

        float acc[3][4][4];
#pragma unroll
        for (int w = 0; w < 3; ++w)
#pragma unroll
            for (int i = 0; i < 4; ++i)
#pragma unroll
                for (int j = 0; j < 4; ++j) acc[w][i][j] = 0.0f;

        for (int k0 = 0; k0 < CC; k0 += 16) {
            __syncthreads();   // protect LDS reads of previous iter
            // stage X: thread (kk=tid>>4, col=4*(tid&15)) -> one float4
            {
                int kk = tid >> 4;
                int col = (tid & 15) * 4;
                *(float4*)&Xs[kk][col] =
                    *(const float4*)&xb[(size_t)(k0 + kk) * NN + n0 + col];
            }
            // stage W x3, transposed into [kk][row]
#pragma unroll
            for (int w = 0; w < 3; ++w) {
#pragma unroll
                for (int i = tid; i < 1024; i += 256) {
                    int kk = i & 15;
                    int r = i >> 4;
                    Ws[w][kk][r] = Wall[w][(size_t)(c0 + r) * CC + k0 + kk];
                }
            }
            __syncthreads();

#pragma unroll
            for (int kk = 0; kk < 16; ++kk) {
                float4 xv = *(float4*)&Xs[kk][4 * tx];
                const float xarr[4] = {xv.x, xv.y, xv.z, xv.w};
#pragma unroll
                for (int w = 0; w < 3; ++w) {
                    float4 av = *(float4*)&Ws[w][kk][4 * ty];
                    const float aarr[4] = {av.x, av.y, av.z, av.w};
#pragma unroll
                    for (int i = 0; i < 4; ++i)
#pragma unroll
                        for (int j = 0; j < 4; ++j)
                            acc[w][i][j] += aarr[i] * xarr[j];
                }
            }
        }

        // epilogue: BN + LIF -> nibble -> octet shfl-OR -> global packed word
#pragma unroll
        for (int w = 0; w < 3; ++w) {
#pragma unroll
            for (int i = 0; i < 4; ++i) {
                uint32_t nib = 0;
#pragma unroll
                for (int j = 0; j < 4; ++j) {
                    float y = acc[w][i][j] * inv_c[w][i] + add_c[w][i];
                    float m2 = mem[w][i][j] * TAU + y;
                    bool s = m2 > THRESH;
                    nib |= (s ? 1u : 0u) << j;
                    mem[w][i][j] = s ? 0.0f : m2;
                }
                uint32_t word = nib << (4 * (tx & 7));
                word |= (uint32_t)__shfl_xor((int)word, 1);
                word |= (uint32_t)__shfl_xor((int)word, 2);
                word |= (uint32_t)__shfl_xor((int)word, 4);
                if ((tx & 7) == 0) {
                    outp[w][(size_t)(b * CC + c0 + 4 * ty + i) * NW +
                            (n0 >> 5) + (tx >> 3)] = word;
                }
            }
        }
    }
}

// ---------------------------------------------------------------------------
// Kernel 2: fused attention + LIF3 on packed spikes (unchanged, verified).
// out[d][n] = SCALE * sum_dp M[d][dp] * q[dp][n],  M[d][dp] = popc(v[d]&k[dp]).
// Grid: (4 n-chunks, NH, BE). Block 256. Loops t inside; membrane in registers.
// ---------------------------------------------------------------------------
__global__ __launch_bounds__(256) void attn_lif_kernel(
    const uint32_t* __restrict__ qp,
    const uint32_t* __restrict__ kp,
    const uint32_t* __restrict__ vp,
    uint32_t* __restrict__ s3p)
{
    __shared__ uint32_t kL[64][NW + 1];
    __shared__ uint32_t vL[64][NW + 1];
    __shared__ float    Msh[64][64 + 1];
    __shared__ uint32_t qL[64][5];

    const int tid = threadIdx.x;
    const int nchunk = blockIdx.x;
    const int h = blockIdx.y;
    const int be = blockIdx.z;
    const int d_own = tid >> 2;
    const int nw_own = tid & 3;

    float mem[32];
#pragma unroll
    for (int i = 0; i < 32; ++i) mem[i] = 0.0f;

    for (int t = 0; t < TT; ++t) {
        const int b = t * BE + be;
        const size_t base_row = (size_t)(b * CC + h * GD);

        for (int i = tid; i < 64 * NW; i += 256) {
            int r = i >> 4;
            int w = i & (NW - 1);
            kL[r][w] = kp[(base_row + r) * NW + w];
            vL[r][w] = vp[(base_row + r) * NW + w];
        }
        {
            int r = tid >> 2;
            int w = tid & 3;
            qL[r][w] = qp[(base_row + r) * NW + nchunk * 4 + w];
        }
        __syncthreads();

        for (int e = tid; e < 64 * 64; e += 256) {
            int d = e >> 6;
            int dp = e & 63;
            int s = 0;
#pragma unroll
            for (int w = 0; w < NW; ++w) s += __popc(vL[d][w] & kL[dp][w]);
            Msh[d][dp] = (float)s;
        }
        __syncthreads();

        float acc[32];
#pragma unroll
        for (int i = 0; i < 32; ++i) acc[i] = 0.0f;

        for (int dp = 0; dp < 64; ++dp) {
            float Mv = Msh[d_own][dp];
            uint32_t w = qL[dp][nw_own];
#pragma unroll
            for (int b2 = 0; b2 < 32; ++b2) {
                acc[b2] += ((w >> b2) & 1u) ? Mv : 0.0f;
            }
        }

        uint32_t sw = 0;
#pragma unroll
        for (int b2 = 0; b2 < 32; ++b2) {
            float m2 = mem[b2] * TAU + SCALE * acc[b2];
            bool s = m2 > THRESH;
            sw |= (s ? 1u : 0u) << b2;
            mem[b2] = s ? 0.0f : m2;
        }
        s3p[(base_row + d_own) * NW + nchunk * 4 + nw_own] = sw;
        __syncthreads();
    }
}

// ---------------------------------------------------------------------------
// Kernel 3: projection conv + BN on packed spikes -> fp32 output (unchanged).
// Grid (NN/64, CC/64, BB). Block 256, 4x4 micro-tile.
// ---------------------------------------------------------------------------
__global__ __launch_bounds__(256) void proj_kernel(
    const uint32_t* __restrict__ s3p,
    const float* __restrict__ W,
    const float* __restrict__ bn_g,
    const float* __restrict__ bn_b,
    const float* __restrict__ bn_m,
    const float* __restrict__ bn_v,
    float* __restrict__ out)
{
    __shared__ float Ws[16][64 + 1];
    __shared__ float Xs[16][64 + 1];

    const int tid = threadIdx.x;
    const int tx = tid & 15;
    const int ty = tid >> 4;
    const int n0 = blockIdx.x * 64;
    const int c0 = blockIdx.y * 64;
    const int b = blockIdx.z;

    float inv_c[4], add_c[4];
#pragma unroll
    for (int i = 0; i < 4; ++i) {
        int c = c0 + ty + 16 * i;
        float g = bn_g[3 * CC + c];
        float bt = bn_b[3 * CC + c];
        float m = bn_m[3 * CC + c];
        float v = bn_v[3 * CC + c];
        float inv = g / sqrtf(v + EPS);
        inv_c[i] = inv;
        add_c[i] = bt - m * inv;
    }

    float acc[4][4];
#pragma unroll
    for (int i = 0; i < 4; ++i)
#pragma unroll
        for (int j = 0; j < 4; ++j) acc[i][j] = 0.0f;

    for (int k0 = 0; k0 < CC; k0 += 16) {
#pragma unroll
        for (int i = tid; i < 1024; i += 256) {
            int kk = i & 15;
            int r = i >> 4;
            Ws[kk][r] = W[(size_t)(c0 + r) * CC + k0 + kk];
        }
#pragma unroll
        for (int i = tid; i < 1024; i += 256) {
            int col = i & 63;
            int kk = i >> 6;
            uint32_t word = s3p[(size_t)(b * CC + k0 + kk) * NW + (n0 >> 5) + (col >> 5)];
            Xs[kk][col] = (float)((word >> (col & 31)) & 1u);
        }
        __syncthreads();

#pragma unroll
        for (int kk = 0; kk < 16; ++kk) {
            float a[4], bvals[4];
#pragma unroll
            for (int i = 0; i < 4; ++i) a[i] = Ws[kk][ty + 16 * i];
#pragma unroll
            for (int j = 0; j < 4; ++j) bvals[j] = Xs[kk][tx + 16 * j];
#pragma unroll
            for (int i = 0; i < 4; ++i)
#pragma unroll
                for (int j = 0; j < 4; ++j) acc[i][j] += a[i] * bvals[j];
        }
        __syncthreads();
    }

    float* ob = out + (size_t)b * CC * NN;
#pragma unroll
    for (int i = 0; i < 4; ++i) {
        int c = c0 + ty + 16 * i;
#pragma unroll
        for (int j = 0; j < 4; ++j) {
            int n = n0 + tx + 16 * j;
            ob[(size_t)c * NN + n] = acc[i][j] * inv_c[i] + add_c[i];
        }
    }
}

// ---------------------------------------------------------------------------
extern "C" void kernel_launch(void* const* d_in, const int* in_sizes, int n_in,
                              void* d_out, int out_size, void* d_ws, size_t ws_size,
                              hipStream_t stream) {
    const float* x     = (const float*)d_in[0];
    const float* wq    = (const float*)d_in[1];
    const float* wk    = (const float*)d_in[2];
    const float* wv    = (const float*)d_in[3];
    const float* wproj = (const float*)d_in[4];
    const float* bng   = (const float*)d_in[5];
    const float* bnb   = (const float*)d_in[6];
    const float* bnm   = (const float*)d_in[7];
    const float* bnv   = (const float*)d_in[8];

    const size_t PK = (size_t)BB * CC * NW;            // 2 MiB each
    uint32_t* qp  = (uint32_t*)d_ws;
    uint32_t* kp  = qp + PK;
    uint32_t* vp  = kp + PK;
    uint32_t* s3p = vp + PK;                           // total 8 MiB

    dim3 gconv(NN / 64, CC / 64, BE);
    conv_qkv_kernel<<<gconv, 256, 0, stream>>>(x, wq, wk, wv, bng, bnb, bnm, bnv,
                                               qp, kp, vp);

    dim3 gattn(4, NH, BE);
    attn_lif_kernel<<<gattn, 256, 0, stream>>>(qp, kp, vp, s3p);

    dim3 gproj(NN / 64, CC / 64, BB);
    proj_kernel<<<gproj, 256, 0, stream>>>(s3p, wproj, bng, bnb, bnm, bnv, (float*)d_out);
}

// Round 8
// 1168.435 us; speedup vs baseline: 2.0454x; 2.0089x over previous
//
#include <hip/hip_runtime.h>
#include <hip/hip_bf16.h>
#include <stdint.h>

// Problem constants
#define TT 4
#define BE 16
#define BB 64          // TT * BE
#define CC 512
#define NN 512
#define NH 8
#define GD 64          // CC / NH
#define NW 16          // NN/32 packed words per (b,c) row
#define TAU 0.5f
#define THRESH 1.0f
#define SCALE 0.125f
#define EPS 1e-5f

// ---------------------------------------------------------------------------
// Kernel 1: 1x1-conv + BN + LIF over T -> bit-packed spikes. One of q/k/v per
// blockIdx.z group: z = w*BE + be (w = 0,1,2), so all three GEMMs run as one
// grid-parallel dispatch with NO extra per-thread state (R7 lesson).
// Block tile: 64 c-rows x 128 n-cols, 256 threads, micro-tile 4 rows x 8 cols
// (cols 4tx..4tx+3 and 64+4tx..64+4tx+3 -> all LDS reads <=2-way/broadcast).
// ---------------------------------------------------------------------------
__global__ __launch_bounds__(256) void conv_bn_lif_kernel(
    const float* __restrict__ x,      // [BB, CC, NN]
    const float* __restrict__ Wq,     // [CC, CC] (out, in)
    const float* __restrict__ Wk,
    const float* __restrict__ Wv,
    const float* __restrict__ bn_g,   // [4, CC]
    const float* __restrict__ bn_b,
    const float* __restrict__ bn_m,
    const float* __restrict__ bn_v,
    uint32_t* __restrict__ qp,        // [BB*CC, NW] packed
    uint32_t* __restrict__ kp,
    uint32_t* __restrict__ vp)
{
    __shared__ float Xs[16][132];     // [kk][col] 128 cols, stride 132 (16B-mult)
    __shared__ float Ws_s[16][68];    // [kk][row] 64 rows, stride 68 (16B-mult)

    const int tid = threadIdx.x;
    const int tx = tid & 15;          // col group
    const int ty = tid >> 4;          // row group: rows c0+4ty..+3
    const int n0 = blockIdx.x * 128;
    const int c0 = blockIdx.y * 64;
    const int z  = blockIdx.z;
    const int be = z & (BE - 1);
    const int w  = z >> 4;            // 0=q 1=k 2=v

    const float* W = (w == 0) ? Wq : (w == 1) ? Wk : Wv;
    uint32_t* outp = (w == 0) ? qp : (w == 1) ? kp : vp;

    float inv_c[4], add_c[4];
#pragma unroll
    for (int i = 0; i < 4; ++i) {
        int c = c0 + 4 * ty + i;
        float g = bn_g[w * CC + c];
        float b = bn_b[w * CC + c];
        float m = bn_m[w * CC + c];
        float v = bn_v[w * CC + c];
        float inv = g / sqrtf(v + EPS);
        inv_c[i] = inv;
        add_c[i] = b - m * inv;
    }

    float mem[4][8];
#pragma unroll
    for (int i = 0; i < 4; ++i)
#pragma unroll
        for (int j = 0; j < 8; ++j) mem[i][j] = 0.0f;

    // W-staging thread mapping (constant across k0): r = tid>>2, kw = tid&3
    const int wr = tid >> 2;
    const int wkw = tid & 3;

    for (int t = 0; t < TT; ++t) {
        const int b = t * BE + be;
        const float* xb = x + (size_t)b * CC * NN;

        float acc[4][8];
#pragma unroll
        for (int i = 0; i < 4; ++i)
#pragma unroll
            for (int j = 0; j < 8; ++j) acc[i][j] = 0.0f;

        for (int k0 = 0; k0 < CC; k0 += 16) {
            __syncthreads();
            // stage X: 512 float4s, 2 per thread (coalesced global)
#pragma unroll
            for (int s = 0; s < 2; ++s) {
                int f = tid + s * 256;
                int kk = f >> 5;          // 32 float4 per row
                int colf = f & 31;
                *(float4*)&Xs[kk][4 * colf] =
                    *(const float4*)&xb[(size_t)(k0 + kk) * NN + n0 + 4 * colf];
            }
            // stage W: one float4 along K per thread, 4 scalar LDS writes (2-way)
            {
                float4 wv4 = *(const float4*)&W[(size_t)(c0 + wr) * CC + k0 + 4 * wkw];
                Ws_s[4 * wkw + 0][wr] = wv4.x;
                Ws_s[4 * wkw + 1][wr] = wv4.y;
                Ws_s[4 * wkw + 2][wr] = wv4.z;
                Ws_s[4 * wkw + 3][wr] = wv4.w;
            }
            __syncthreads();

#pragma unroll
            for (int kk = 0; kk < 16; ++kk) {
                float4 av = *(float4*)&Ws_s[kk][4 * ty];          // broadcast
                float4 xlo = *(float4*)&Xs[kk][4 * tx];           // 2-way
                float4 xhi = *(float4*)&Xs[kk][64 + 4 * tx];      // 2-way
                const float a[4] = {av.x, av.y, av.z, av.w};
                const float xl[4] = {xlo.x, xlo.y, xlo.z, xlo.w};
                const float xh[4] = {xhi.x, xhi.y, xhi.z, xhi.w};
#pragma unroll
                for (int i = 0; i < 4; ++i) {
#pragma unroll
                    for (int j = 0; j < 4; ++j) {
                        acc[i][j] += a[i] * xl[j];
                        acc[i][4 + j] += a[i] * xh[j];
                    }
                }
            }
        }

        // epilogue: BN + LIF -> two nibbles/row -> octet shfl-OR -> global word
#pragma unroll
        for (int i = 0; i < 4; ++i) {
            uint32_t nibLo = 0, nibHi = 0;
#pragma unroll
            for (int j = 0; j < 4; ++j) {
                float y = acc[i][j] * inv_c[i] + add_c[i];
                float m2 = mem[i][j] * TAU + y;
                bool s = m2 > THRESH;
                nibLo |= (s ? 1u : 0u) << j;
                mem[i][j] = s ? 0.0f : m2;

                float y2 = acc[i][4 + j] * inv_c[i] + add_c[i];
                float m22 = mem[i][4 + j] * TAU + y2;
                bool s2 = m22 > THRESH;
                nibHi |= (s2 ? 1u : 0u) << j;
                mem[i][4 + j] = s2 ? 0.0f : m22;
            }
            const size_t rowbase = (size_t)(b * CC + c0 + 4 * ty + i) * NW + (n0 >> 5);
            uint32_t wlo = nibLo << (4 * (tx & 7));
            wlo |= (uint32_t)__shfl_xor((int)wlo, 1);
            wlo |= (uint32_t)__shfl_xor((int)wlo, 2);
            wlo |= (uint32_t)__shfl_xor((int)wlo, 4);
            uint32_t whi = nibHi << (4 * (tx & 7));
            whi |= (uint32_t)__shfl_xor((int)whi, 1);
            whi |= (uint32_t)__shfl_xor((int)whi, 2);
            whi |= (uint32_t)__shfl_xor((int)whi, 4);
            if ((tx & 7) == 0) {
                outp[rowbase + (tx >> 3)] = wlo;
                outp[rowbase + 2 + (tx >> 3)] = whi;
            }
        }
    }
}

// ---------------------------------------------------------------------------
// Kernel 2: fused attention + LIF3 on packed spikes (unchanged, verified).
// out[d][n] = SCALE * sum_dp M[d][dp] * q[dp][n],  M[d][dp] = popc(v[d]&k[dp]).
// ---------------------------------------------------------------------------
__global__ __launch_bounds__(256) void attn_lif_kernel(
    const uint32_t* __restrict__ qp,
    const uint32_t* __restrict__ kp,
    const uint32_t* __restrict__ vp,
    uint32_t* __restrict__ s3p)
{
    __shared__ uint32_t kL[64][NW + 1];
    __shared__ uint32_t vL[64][NW + 1];
    __shared__ float    Msh[64][64 + 1];
    __shared__ uint32_t qL[64][5];

    const int tid = threadIdx.x;
    const int nchunk = blockIdx.x;
    const int h = blockIdx.y;
    const int be = blockIdx.z;
    const int d_own = tid >> 2;
    const int nw_own = tid & 3;

    float mem[32];
#pragma unroll
    for (int i = 0; i < 32; ++i) mem[i] = 0.0f;

    for (int t = 0; t < TT; ++t) {
        const int b = t * BE + be;
        const size_t base_row = (size_t)(b * CC + h * GD);

        for (int i = tid; i < 64 * NW; i += 256) {
            int r = i >> 4;
            int w = i & (NW - 1);
            kL[r][w] = kp[(base_row + r) * NW + w];
            vL[r][w] = vp[(base_row + r) * NW + w];
        }
        {
            int r = tid >> 2;
            int w = tid & 3;
            qL[r][w] = qp[(base_row + r) * NW + nchunk * 4 + w];
        }
        __syncthreads();

        for (int e = tid; e < 64 * 64; e += 256) {
            int d = e >> 6;
            int dp = e & 63;
            int s = 0;
#pragma unroll
            for (int w = 0; w < NW; ++w) s += __popc(vL[d][w] & kL[dp][w]);
            Msh[d][dp] = (float)s;
        }
        __syncthreads();

        float acc[32];
#pragma unroll
        for (int i = 0; i < 32; ++i) acc[i] = 0.0f;

        for (int dp = 0; dp < 64; ++dp) {
            float Mv = Msh[d_own][dp];
            uint32_t w = qL[dp][nw_own];
#pragma unroll
            for (int b2 = 0; b2 < 32; ++b2) {
                acc[b2] += ((w >> b2) & 1u) ? Mv : 0.0f;
            }
        }

        uint32_t sw = 0;
#pragma unroll
        for (int b2 = 0; b2 < 32; ++b2) {
            float m2 = mem[b2] * TAU + SCALE * acc[b2];
            bool s = m2 > THRESH;
            sw |= (s ? 1u : 0u) << b2;
            mem[b2] = s ? 0.0f : m2;
        }
        s3p[(base_row + d_own) * NW + nchunk * 4 + nw_own] = sw;
        __syncthreads();
    }
}

// ---------------------------------------------------------------------------
// Kernel 3: projection conv + BN on packed spikes -> fp32 output.
// Same 64x128 tile / 4x8 micro-tile structure as kernel 1 (no LIF state).
// Grid (NN/128, CC/64, BB).
// ---------------------------------------------------------------------------
__global__ __launch_bounds__(256) void proj_kernel(
    const uint32_t* __restrict__ s3p,          // [BB*CC, NW] packed
    const float* __restrict__ W,               // [CC, CC]
    const float* __restrict__ bn_g,
    const float* __restrict__ bn_b,
    const float* __restrict__ bn_m,
    const float* __restrict__ bn_v,
    float* __restrict__ out)                   // [BB, CC, NN]
{
    __shared__ float Xs[16][132];
    __shared__ float Ws_s[16][68];

    const int tid = threadIdx.x;
    const int tx = tid & 15;
    const int ty = tid >> 4;
    const int n0 = blockIdx.x * 128;
    const int c0 = blockIdx.y * 64;
    const int b = blockIdx.z;

    float inv_c[4], add_c[4];
#pragma unroll
    for (int i = 0; i < 4; ++i) {
        int c = c0 + 4 * ty + i;
        float g = bn_g[3 * CC + c];
        float bt = bn_b[3 * CC + c];
        float m = bn_m[3 * CC + c];
        float v = bn_v[3 * CC + c];
        float inv = g / sqrtf(v + EPS);
        inv_c[i] = inv;
        add_c[i] = bt - m * inv;
    }

    const int wr = tid >> 2;
    const int wkw = tid & 3;

    float acc[4][8];
#pragma unroll
    for (int i = 0; i < 4; ++i)
#pragma unroll
        for (int j = 0; j < 8; ++j) acc[i][j] = 0.0f;

    for (int k0 = 0; k0 < CC; k0 += 16) {
        __syncthreads();
        // stage X from packed spikes: 2 float4 per thread
#pragma unroll
        for (int s = 0; s < 2; ++s) {
            int f = tid + s * 256;
            int kk = f >> 5;
            int colf = f & 31;
            uint32_t word = s3p[(size_t)(b * CC + k0 + kk) * NW + (n0 >> 5) + (colf >> 3)];
            int sh = 4 * (colf & 7);
            float4 xv;
            xv.x = (float)((word >> (sh + 0)) & 1u);
            xv.y = (float)((word >> (sh + 1)) & 1u);
            xv.z = (float)((word >> (sh + 2)) & 1u);
            xv.w = (float)((word >> (sh + 3)) & 1u);
            *(float4*)&Xs[kk][4 * colf] = xv;
        }
        {
            float4 wv4 = *(const float4*)&W[(size_t)(c0 + wr) * CC + k0 + 4 * wkw];
            Ws_s[4 * wkw + 0][wr] = wv4.x;
            Ws_s[4 * wkw + 1][wr] = wv4.y;
            Ws_s[4 * wkw + 2][wr] = wv4.z;
            Ws_s[4 * wkw + 3][wr] = wv4.w;
        }
        __syncthreads();

#pragma unroll
        for (int kk = 0; kk < 16; ++kk) {
            float4 av = *(float4*)&Ws_s[kk][4 * ty];
            float4 xlo = *(float4*)&Xs[kk][4 * tx];
            float4 xhi = *(float4*)&Xs[kk][64 + 4 * tx];
            const float a[4] = {av.x, av.y, av.z, av.w};
            const float xl[4] = {xlo.x, xlo.y, xlo.z, xlo.w};
            const float xh[4] = {xhi.x, xhi.y, xhi.z, xhi.w};
#pragma unroll
            for (int i = 0; i < 4; ++i) {
#pragma unroll
                for (int j = 0; j < 4; ++j) {
                    acc[i][j] += a[i] * xl[j];
                    acc[i][4 + j] += a[i] * xh[j];
                }
            }
        }
    }

    float* ob = out + (size_t)b * CC * NN;
#pragma unroll
    for (int i = 0; i < 4; ++i) {
        int c = c0 + 4 * ty + i;
        float4 lo, hi;
        lo.x = acc[i][0] * inv_c[i] + add_c[i];
        lo.y = acc[i][1] * inv_c[i] + add_c[i];
        lo.z = acc[i][2] * inv_c[i] + add_c[i];
        lo.w = acc[i][3] * inv_c[i] + add_c[i];
        hi.x = acc[i][4] * inv_c[i] + add_c[i];
        hi.y = acc[i][5] * inv_c[i] + add_c[i];
        hi.z = acc[i][6] * inv_c[i] + add_c[i];
        hi.w = acc[i][7] * inv_c[i] + add_c[i];
        *(float4*)&ob[(size_t)c * NN + n0 + 4 * tx] = lo;
        *(float4*)&ob[(size_t)c * NN + n0 + 64 + 4 * tx] = hi;
    }
}

// ---------------------------------------------------------------------------
extern "C" void kernel_launch(void* const* d_in, const int* in_sizes, int n_in,
                              void* d_out, int out_size, void* d_ws, size_t ws_size,
                              hipStream_t stream) {
    const float* x     = (const float*)d_in[0];
    const float* wq    = (const float*)d_in[1];
    const float* wk    = (const float*)d_in[2];
    const float* wv    = (const float*)d_in[3];
    const float* wproj = (const float*)d_in[4];
    const float* bng   = (const float*)d_in[5];
    const float* bnb   = (const float*)d_in[6];
    const float* bnm   = (const float*)d_in[7];
    const float* bnv   = (const float*)d_in[8];

    const size_t PK = (size_t)BB * CC * NW;            // 2 MiB each
    uint32_t* qp  = (uint32_t*)d_ws;
    uint32_t* kp  = qp + PK;
    uint32_t* vp  = kp + PK;
    uint32_t* s3p = vp + PK;                           // total 8 MiB

    dim3 gconv(NN / 128, CC / 64, 3 * BE);             // z = w*16 + be
    conv_bn_lif_kernel<<<gconv, 256, 0, stream>>>(x, wq, wk, wv, bng, bnb, bnm, bnv,
                                                  qp, kp, vp);

    dim3 gattn(4, NH, BE);
    attn_lif_kernel<<<gattn, 256, 0, stream>>>(qp, kp, vp, s3p);

    dim3 gproj(NN / 128, CC / 64, BB);
    proj_kernel<<<gproj, 256, 0, stream>>>(s3p, wproj, bng, bnb, bnm, bnv, (float*)d_out);
}